// Round 1
// baseline (2203.062 us; speedup 1.0000x reference)
//
#include <hip/hip_runtime.h>
#include <cmath>

#define BN_EPS 1e-5f
#define CLAMPV 1e-4f

static constexpr int B = 32, C = 1536, T = 1000, A = 128;
static constexpr int C3 = 3 * C;

// ws layout (float offsets)
static constexpr size_t W1T_OFF  = 0;                       // 4608*128 = 589824
static constexpr size_t MEAN_OFF = 589824;                  // B*C = 49152
static constexpr size_t STD_OFF  = MEAN_OFF + 49152;
static constexpr size_t BIAS_OFF = STD_OFF + 49152;         // B*A = 4096
static constexpr size_t HT_OFF   = BIAS_OFF + 4096;         // B*T*A = 4096000

// ---------------- kernel 0: transpose W1 (A x 3C) -> W1T (3C x A) ----------------
__global__ __launch_bounds__(256) void k_transpose(const float* __restrict__ W1,
                                                   float* __restrict__ W1T) {
  __shared__ float tile[32][33];
  int bx = blockIdx.x;            // 3C/32 = 144
  int by = blockIdx.y;            // A/32 = 4
  int tx = threadIdx.x;           // 0..31
  int ty = threadIdx.y;           // 0..7
  int c0 = bx * 32, o0 = by * 32;
#pragma unroll
  for (int k = 0; k < 32; k += 8)
    tile[ty + k][tx] = W1[(size_t)(o0 + ty + k) * C3 + c0 + tx];
  __syncthreads();
#pragma unroll
  for (int k = 0; k < 32; k += 8)
    W1T[(size_t)(c0 + ty + k) * A + o0 + tx] = tile[tx][ty + k];
}

// ---------------- kernel 1: per-(b,c) mean / std over T ----------------
__global__ __launch_bounds__(256) void k_stats(const float* __restrict__ x,
                                               float* __restrict__ mean,
                                               float* __restrict__ stdv) {
  int row  = blockIdx.x * 4 + (threadIdx.x >> 6);   // b*C + c
  int lane = threadIdx.x & 63;
  const float2* xr2 = (const float2*)(x + (size_t)row * T);
  float s1 = 0.f, s2 = 0.f;
#pragma unroll 4
  for (int j = lane; j < T / 2; j += 64) {
    float2 v = xr2[j];
    s1 += v.x + v.y;
    s2 += v.x * v.x + v.y * v.y;
  }
#pragma unroll
  for (int off = 32; off; off >>= 1) {
    s1 += __shfl_xor(s1, off);
    s2 += __shfl_xor(s2, off);
  }
  if (lane == 0) {
    float m   = s1 / T;
    float var = (s2 - s1 * m) / (T - 1);            // = sum((x-m)^2)/(T-1)
    mean[row] = m;
    stdv[row] = sqrtf(fmaxf(var, CLAMPV));
  }
}

// ---------------- kernel 2: bias1[b,o] = mean@WmT + std@WsT + b1 ----------------
__global__ __launch_bounds__(128) void k_bias(const float* __restrict__ W1T,
                                              const float* __restrict__ b1,
                                              const float* __restrict__ mean,
                                              const float* __restrict__ stdv,
                                              float* __restrict__ bias1) {
  __shared__ float sm[C], ss[C];
  int b = blockIdx.x;
  int o = threadIdx.x;            // 128 threads
  for (int c = o; c < C; c += 128) {
    sm[c] = mean[b * C + c];
    ss[c] = stdv[b * C + c];
  }
  __syncthreads();
  const float* WmT = W1T + (size_t)C * A;       // rows [C, 2C)
  const float* WsT = W1T + (size_t)2 * C * A;   // rows [2C, 3C)
  float acc = b1[o];
#pragma unroll 4
  for (int c = 0; c < C; c++)
    acc += sm[c] * WmT[(size_t)c * A + o] + ss[c] * WsT[(size_t)c * A + o];
  bias1[b * A + o] = acc;
}

// ---------------- kernel 3: GEMM1 + relu + bn1 + tanh -> ht[b][t][o] ----------------
// block (b, tt): 4 waves, wave w = c-quarter, lane = t within 64-tile.
// acc[128] per lane (all o). LDS combine (swizzled) in two o-halves.
__global__ __launch_bounds__(256, 2) void k_gemm1(const float* __restrict__ x,
                                                  const float* __restrict__ W1T,
                                                  const float* __restrict__ bias1,
                                                  const float* __restrict__ g1,
                                                  const float* __restrict__ beta1,
                                                  const float* __restrict__ rm1,
                                                  const float* __restrict__ rv1,
                                                  float* __restrict__ ht) {
  int b    = blockIdx.x;
  int tt   = blockIdx.y;                 // 16 tiles of 64 t
  int wid  = threadIdx.x >> 6;
  int lane = threadIdx.x & 63;
  int t    = tt * 64 + lane;
  bool tvalid = t < T;

  float acc[128];
#pragma unroll
  for (int i = 0; i < 128; i++) acc[i] = 0.f;

  const float* xcol = x + (size_t)b * C * T + t;
  int c0 = wid * (C / 4), c1 = c0 + C / 4;
  for (int c = c0; c < c1; c++) {
    float xv = tvalid ? xcol[(size_t)c * T] : 0.f;
    const float4* wr = (const float4*)(W1T + (size_t)c * A);  // uniform row -> s_load
#pragma unroll
    for (int j = 0; j < 32; j++) {
      float4 w = wr[j];
      acc[4 * j + 0] += w.x * xv;
      acc[4 * j + 1] += w.y * xv;
      acc[4 * j + 2] += w.z * xv;
      acc[4 * j + 3] += w.w * xv;
    }
  }

  __shared__ float red[4][64][64];   // 64 KB, reused for both o-halves
  int swz = (lane & 7) << 2;
#pragma unroll
  for (int h = 0; h < 2; h++) {
    __syncthreads();
#pragma unroll
    for (int j = 0; j < 16; j++) {
      int os = (4 * j) ^ swz;        // swizzled address, static value index
      red[wid][lane][os + 0] = acc[h * 64 + 4 * j + 0];
      red[wid][lane][os + 1] = acc[h * 64 + 4 * j + 1];
      red[wid][lane][os + 2] = acc[h * 64 + 4 * j + 2];
      red[wid][lane][os + 3] = acc[h * 64 + 4 * j + 3];
    }
    __syncthreads();
#pragma unroll
    for (int i = 0; i < 16; i++) {
      int idx = threadIdx.x + 256 * i;
      int tl = idx >> 6, ol = idx & 63;
      int tg = tt * 64 + tl;
      float sum = 0.f;
#pragma unroll
      for (int w = 0; w < 4; w++) sum += red[w][tl][ol ^ ((tl & 7) << 2)];
      if (tg < T) {
        int o = h * 64 + ol;
        float v   = sum + bias1[b * A + o];
        float r   = fmaxf(v, 0.f);
        float inv = g1[o] * rsqrtf(rv1[o] + BN_EPS);
        float hv  = tanhf(r * inv + (beta1[o] - rm1[o] * inv));
        ht[((size_t)b * T + tg) * A + o] = hv;
      }
    }
  }
}

// ---------------- kernel 4: GEMM2 + relu + bn2 + online softmax + pooling ----------------
// block (b, cb of 64 channels): 4 waves = 4 t-quarters of 250; lane = channel.
// W2 row (128 f) in VGPRs; ht row (uniform) via scalar loads; flash-style m/s/p/q.
__global__ __launch_bounds__(256, 2) void k_pool(const float* __restrict__ x,
                                                 const float* __restrict__ ht,
                                                 const float* __restrict__ W2,
                                                 const float* __restrict__ b2,
                                                 const float* __restrict__ g2,
                                                 const float* __restrict__ beta2,
                                                 const float* __restrict__ rm2,
                                                 const float* __restrict__ rv2,
                                                 float* __restrict__ out) {
  int b    = blockIdx.x;
  int cb   = blockIdx.y;                  // 24 blocks of 64 channels
  int wid  = threadIdx.x >> 6;
  int lane = threadIdx.x & 63;
  int c    = cb * 64 + lane;

  float4 w2[32];
  const float4* wr = (const float4*)(W2 + (size_t)c * A);
#pragma unroll
  for (int j = 0; j < 32; j++) w2[j] = wr[j];

  float inv = g2[c] * rsqrtf(rv2[c] + BN_EPS);
  float sh  = beta2[c] - rm2[c] * inv;
  float bb  = b2[c];

  float m = -1e30f, s = 0.f, p = 0.f, q = 0.f;
  const float2* xr  = (const float2*)(x + ((size_t)b * C + c) * T + wid * 250);
  const float* hbase = ht + ((size_t)b * T + wid * 250) * A;

  for (int i = 0; i < 125; i++) {
    float2 xv = xr[i];
#pragma unroll
    for (int u = 0; u < 2; u++) {
      const float4* hr = (const float4*)(hbase + (size_t)(2 * i + u) * A);  // uniform -> s_load
      float h2 = bb;
#pragma unroll
      for (int j = 0; j < 32; j++) {
        float4 hv = hr[j];
        h2 += w2[j].x * hv.x + w2[j].y * hv.y + w2[j].z * hv.z + w2[j].w * hv.w;
      }
      float z  = fmaxf(h2, 0.f) * inv + sh;
      float xs = u ? xv.y : xv.x;
      float nm = fmaxf(m, z);
      float ea = __expf(m - nm);
      float eb = __expf(z - nm);
      s = s * ea + eb;
      p = p * ea + xs * eb;
      q = q * ea + xs * xs * eb;
      m = nm;
    }
  }

  __shared__ float red[4][64][4];
  red[wid][lane][0] = m;
  red[wid][lane][1] = s;
  red[wid][lane][2] = p;
  red[wid][lane][3] = q;
  __syncthreads();
  if (threadIdx.x < 64) {
    float M = -1e30f;
#pragma unroll
    for (int w = 0; w < 4; w++) M = fmaxf(M, red[w][lane][0]);
    float S = 0.f, P = 0.f, Q = 0.f;
#pragma unroll
    for (int w = 0; w < 4; w++) {
      float e = __expf(red[w][lane][0] - M);
      S += red[w][lane][1] * e;
      P += red[w][lane][2] * e;
      Q += red[w][lane][3] * e;
    }
    float mu  = P / S;
    float var = Q / S - mu * mu;
    float sg  = sqrtf(fmaxf(var, CLAMPV));
    int cc = cb * 64 + lane;
    out[(size_t)b * (2 * C) + cc]     = mu;
    out[(size_t)b * (2 * C) + C + cc] = sg;
  }
}

extern "C" void kernel_launch(void* const* d_in, const int* in_sizes, int n_in,
                              void* d_out, int out_size, void* d_ws, size_t ws_size,
                              hipStream_t stream) {
  const float* x     = (const float*)d_in[0];
  const float* W1    = (const float*)d_in[1];
  const float* b1    = (const float*)d_in[2];
  const float* g1    = (const float*)d_in[3];
  const float* beta1 = (const float*)d_in[4];
  const float* rm1   = (const float*)d_in[5];
  const float* rv1   = (const float*)d_in[6];
  const float* W2    = (const float*)d_in[7];
  const float* b2    = (const float*)d_in[8];
  const float* g2    = (const float*)d_in[9];
  const float* beta2 = (const float*)d_in[10];
  const float* rm2   = (const float*)d_in[11];
  const float* rv2   = (const float*)d_in[12];

  float* ws    = (float*)d_ws;
  float* W1T   = ws + W1T_OFF;
  float* mean  = ws + MEAN_OFF;
  float* stdv  = ws + STD_OFF;
  float* bias1 = ws + BIAS_OFF;
  float* ht    = ws + HT_OFF;
  float* out   = (float*)d_out;

  k_transpose<<<dim3(C3 / 32, A / 32), dim3(32, 8), 0, stream>>>(W1, W1T);
  k_stats<<<dim3(B * C / 4), dim3(256), 0, stream>>>(x, mean, stdv);
  k_bias<<<dim3(B), dim3(128), 0, stream>>>(W1T, b1, mean, stdv, bias1);
  k_gemm1<<<dim3(B, 16), dim3(256), 0, stream>>>(x, W1T, bias1, g1, beta1, rm1, rv1, ht);
  k_pool<<<dim3(B, 24), dim3(256), 0, stream>>>(x, ht, W2, b2, g2, beta2, rm2, rv2, out);
}

// Round 2
// 558.585 us; speedup vs baseline: 3.9440x; 3.9440x over previous
//
#include <hip/hip_runtime.h>
#include <cmath>

#define BN_EPS 1e-5f
#define CLAMPV 1e-4f

static constexpr int B_ = 32, C_ = 1536, T_ = 1000, A_ = 128;
static constexpr int C3 = 3 * C_;
static constexpr int TP = 1024;        // padded T
static constexpr int KS1 = C_ / 32;    // 48 k-steps GEMM1
static constexpr int KS2 = A_ / 32;    // 4 k-steps GEMM2
static constexpr int OM1 = A_ / 16;    // 8 o-frags GEMM1
static constexpr int OM2 = C_ / 16;    // 96 o-frags GEMM2

using bf16x8 = __attribute__((ext_vector_type(8))) short;
using f32x4  = __attribute__((ext_vector_type(4))) float;

#define MFMA(a, b, c) __builtin_amdgcn_mfma_f32_16x16x32_bf16(a, b, c, 0, 0, 0)

// ---- ws layout (float-unit offsets) ----
static constexpr size_t WT_OFF   = 0;                     // 2C*A = 393216 f
static constexpr size_t MEAN_OFF = 393216;                // B*C
static constexpr size_t STD_OFF  = MEAN_OFF + 49152;
static constexpr size_t BIAS_OFF = STD_OFF + 49152;       // B*A
static constexpr size_t INV1_OFF = BIAS_OFF + 4096;
static constexpr size_t SH1_OFF  = INV1_OFF + 128;
static constexpr size_t INV2_OFF = SH1_OFF + 128;
static constexpr size_t SH2_OFF  = INV2_OFF + 1536;
static constexpr size_t WXH_OFF  = SH2_OFF + 1536;        // 196608 ushort = 98304 f each
static constexpr size_t WXL_OFF  = WXH_OFF + 98304;
static constexpr size_t W2H_OFF  = WXL_OFF + 98304;
static constexpr size_t W2L_OFF  = W2H_OFF + 98304;
static constexpr size_t HTP_OFF  = W2L_OFF + 98304;       // B*A*TP dwords = 4194304
static constexpr size_t SS_OFF   = HTP_OFF + 4194304;     // B*C
static constexpr size_t PP_OFF   = SS_OFF + 49152;
static constexpr size_t QQ_OFF   = PP_OFF + 49152;        // end ~20.9 MB

__device__ __forceinline__ short f2bf(float v) {
  __bf16 b = (__bf16)v;                     // RNE
  return __builtin_bit_cast(short, b);
}
__device__ __forceinline__ float bf2f(short s) {
  unsigned int u = ((unsigned int)(unsigned short)s) << 16;
  return __builtin_bit_cast(float, u);
}

// ---------------- transpose W1 cols [C,3C) -> WT[c'][o] (fp32) ----------------
__global__ __launch_bounds__(256) void k_transpose(const float* __restrict__ W1,
                                                   float* __restrict__ WT) {
  __shared__ float tile[32][33];
  int c0 = blockIdx.x * 32;   // 96 blocks -> c' in [0, 3072)
  int o0 = blockIdx.y * 32;   // 4 blocks
  int tx = threadIdx.x, ty = threadIdx.y;
#pragma unroll
  for (int k = 0; k < 32; k += 8)
    tile[ty + k][tx] = W1[(size_t)(o0 + ty + k) * C3 + C_ + c0 + tx];
  __syncthreads();
#pragma unroll
  for (int k = 0; k < 32; k += 8)
    WT[(size_t)(c0 + ty + k) * A_ + o0 + tx] = tile[tx][ty + k];
}

// ---------------- per-(b,c) mean / std over T ----------------
__global__ __launch_bounds__(256) void k_stats(const float* __restrict__ x,
                                               float* __restrict__ mean,
                                               float* __restrict__ stdv) {
  int row  = blockIdx.x * 4 + (threadIdx.x >> 6);
  int lane = threadIdx.x & 63;
  const float2* xr2 = (const float2*)(x + (size_t)row * T_);
  float s1 = 0.f, s2 = 0.f;
#pragma unroll 4
  for (int j = lane; j < T_ / 2; j += 64) {
    float2 v = xr2[j];
    s1 += v.x + v.y;
    s2 += v.x * v.x + v.y * v.y;
  }
#pragma unroll
  for (int off = 32; off; off >>= 1) {
    s1 += __shfl_xor(s1, off);
    s2 += __shfl_xor(s2, off);
  }
  if (lane == 0) {
    float m   = s1 / T_;
    float var = (s2 - s1 * m) / (T_ - 1);
    mean[row] = m;
    stdv[row] = sqrtf(fmaxf(var, CLAMPV));
  }
}

// ---------------- bn scale/shift precompute ----------------
__global__ void k_bn(const float* __restrict__ g1, const float* __restrict__ beta1,
                     const float* __restrict__ rm1, const float* __restrict__ rv1,
                     const float* __restrict__ g2, const float* __restrict__ beta2,
                     const float* __restrict__ rm2, const float* __restrict__ rv2,
                     float* inv1, float* sh1, float* inv2, float* sh2) {
  int i = blockIdx.x * 256 + threadIdx.x;
  if (i < A_) { float iv = g1[i] * rsqrtf(rv1[i] + BN_EPS); inv1[i] = iv; sh1[i] = beta1[i] - rm1[i] * iv; }
  if (i < C_) { float iv = g2[i] * rsqrtf(rv2[i] + BN_EPS); inv2[i] = iv; sh2[i] = beta2[i] - rm2[i] * iv; }
}

// ---------------- pack Wx and W2 (hi/lo bf16) into MFMA A-frag order ----------------
// frag id = (om*KS + ks)*64 + lane; element j: row = om*16 + (l&15), k = ks*32 + (l>>4)*8 + j
__global__ __launch_bounds__(256) void k_pack_w(const float* __restrict__ W1,
                                                const float* __restrict__ W2,
                                                unsigned short* __restrict__ WxH,
                                                unsigned short* __restrict__ WxL,
                                                unsigned short* __restrict__ W2H,
                                                unsigned short* __restrict__ W2L) {
  int id = blockIdx.x * 256 + threadIdx.x;
  if (id < OM1 * KS1 * 64) {
    int l = id & 63; int ks = (id >> 6) % KS1; int om = id / (64 * KS1);
    int o  = om * 16 + (l & 15);
    int c0 = ks * 32 + (l >> 4) * 8;
#pragma unroll
    for (int j = 0; j < 8; j++) {
      float v = W1[(size_t)o * C3 + c0 + j];   // Wx = first third
      short h = f2bf(v); float fh = bf2f(h); short lo = f2bf(v - fh);
      WxH[(size_t)id * 8 + j] = (unsigned short)h;
      WxL[(size_t)id * 8 + j] = (unsigned short)lo;
    }
  } else {
    int id2 = id - OM1 * KS1 * 64;
    int l = id2 & 63; int ks = (id2 >> 6) & 3; int om = id2 / (64 * KS2);
    int cr = om * 16 + (l & 15);
    int a0 = ks * 32 + (l >> 4) * 8;
#pragma unroll
    for (int j = 0; j < 8; j++) {
      float v = W2[(size_t)cr * A_ + a0 + j];
      short h = f2bf(v); float fh = bf2f(h); short lo = f2bf(v - fh);
      W2H[(size_t)id2 * 8 + j] = (unsigned short)h;
      W2L[(size_t)id2 * 8 + j] = (unsigned short)lo;
    }
  }
}

// ---------------- bias1[b][o] = mean@Wm.T + std@Ws.T + b1 ----------------
__global__ __launch_bounds__(128) void k_bias(const float* __restrict__ WT,
                                              const float* __restrict__ b1,
                                              const float* __restrict__ mean,
                                              const float* __restrict__ stdv,
                                              float* __restrict__ bias1) {
  __shared__ float sm[C_], ss[C_];
  int b = blockIdx.x, o = threadIdx.x;
  for (int c = o; c < C_; c += 128) { sm[c] = mean[b * C_ + c]; ss[c] = stdv[b * C_ + c]; }
  __syncthreads();
  float acc = b1[o];
#pragma unroll 8
  for (int c = 0; c < C_; c++)
    acc += sm[c] * WT[(size_t)c * A_ + o] + ss[c] * WT[(size_t)(C_ + c) * A_ + o];
  bias1[b * A_ + o] = acc;
}

// ---------------- GEMM1 (MFMA, split-3) + bias + relu + bn + tanh -> htP ----------------
// block (b, tt): 128 o x 128 t tile; waves: wm (o-64) x wn (t-64)
__global__ __launch_bounds__(256) void k_gemm1(const float* __restrict__ x,
    const unsigned short* __restrict__ WxH, const unsigned short* __restrict__ WxL,
    const float* __restrict__ bias1, const float* __restrict__ inv1, const float* __restrict__ sh1,
    unsigned int* __restrict__ htP) {
  int b = blockIdx.x, tt = blockIdx.y;
  int wid = threadIdx.x >> 6, l = threadIdx.x & 63;
  int wm = wid >> 1, wn = wid & 1;
  int lg = l >> 4, ll = l & 15;

  f32x4 acc[4][4];
#pragma unroll
  for (int mi = 0; mi < 4; mi++)
#pragma unroll
    for (int ni = 0; ni < 4; ni++) acc[mi][ni] = (f32x4){0.f, 0.f, 0.f, 0.f};

  const float* xb = x + (size_t)b * C_ * T_;
  int tbase = tt * 128 + wn * 64;
  int   tloc[4];
  float tmask[4];
#pragma unroll
  for (int ns = 0; ns < 4; ns++) {
    int t = tbase + ns * 16 + ll;
    tloc[ns]  = t < T_ ? t : T_ - 1;
    tmask[ns] = t < T_ ? 1.f : 0.f;
  }

  for (int ks = 0; ks < KS1; ks++) {
    bf16x8 ah[4], al[4];
#pragma unroll
    for (int mi = 0; mi < 4; mi++) {
      size_t fi = ((size_t)((wm * 4 + mi) * KS1 + ks) * 64 + l) * 8;
      ah[mi] = *(const bf16x8*)(WxH + fi);
      al[mi] = *(const bf16x8*)(WxL + fi);
    }
    int cg = ks * 32 + lg * 8;
    bf16x8 bh[4], bl[4];
#pragma unroll
    for (int ns = 0; ns < 4; ns++) {
      const float* xp = xb + tloc[ns];
      float m = tmask[ns];
#pragma unroll
      for (int j = 0; j < 8; j++) {
        float v = xp[(size_t)(cg + j) * T_] * m;
        short h = f2bf(v); float fh = bf2f(h); short lo = f2bf(v - fh);
        bh[ns][j] = h; bl[ns][j] = lo;
      }
    }
#pragma unroll
    for (int mi = 0; mi < 4; mi++)
#pragma unroll
      for (int ns = 0; ns < 4; ns++) {
        acc[mi][ns] = MFMA(ah[mi], bh[ns], acc[mi][ns]);
        acc[mi][ns] = MFMA(ah[mi], bl[ns], acc[mi][ns]);
        acc[mi][ns] = MFMA(al[mi], bh[ns], acc[mi][ns]);
      }
  }

  // epilogue: bias + relu + bn + tanh, split hi/lo, store packed dword [b][a][t]
#pragma unroll
  for (int mi = 0; mi < 4; mi++) {
#pragma unroll
    for (int r = 0; r < 4; r++) {
      int o = wm * 64 + mi * 16 + lg * 4 + r;
      float bz = bias1[b * A_ + o];
      float iv = inv1[o], sv = sh1[o];
#pragma unroll
      for (int ni = 0; ni < 4; ni++) {
        int t = tbase + ni * 16 + ll;
        float v = acc[mi][ni][r] + bz;
        v = fmaxf(v, 0.f) * iv + sv;
        float e  = __expf(2.f * v);
        float th = 1.f - 2.f / (e + 1.f);      // tanh(v)
        short h = f2bf(th); float fh = bf2f(h); short lo = f2bf(th - fh);
        htP[(size_t)(b * A_ + o) * TP + t] =
            ((unsigned int)(unsigned short)h << 16) | (unsigned short)lo;
      }
    }
  }
}

// ---------------- GEMM2 (MFMA, split-3) + relu + bn + exp-pool partials ----------------
// block (b, cb, th): c-tile 128, t-range = 2 t-tiles of 128; waves wm (c-64) x wn (t-64)
__global__ __launch_bounds__(256) void k_pool(const float* __restrict__ x,
    const unsigned int* __restrict__ htP,
    const unsigned short* __restrict__ W2H, const unsigned short* __restrict__ W2L,
    const float* __restrict__ b2, const float* __restrict__ inv2, const float* __restrict__ sh2,
    float* __restrict__ SS, float* __restrict__ PP, float* __restrict__ QQ) {
  int b = blockIdx.x, cb = blockIdx.y, th = blockIdx.z;
  int wid = threadIdx.x >> 6, l = threadIdx.x & 63;
  int wm = wid >> 1, wn = wid & 1;
  int lg = l >> 4, ll = l & 15;
  int tix = threadIdx.x;

  __shared__ float sb2[128], siv[128], ssh[128];
  __shared__ float rS[2][128], rP[2][128], rQ[2][128];
  if (tix < 128) {
    int c = cb * 128 + tix;
    sb2[tix] = b2[c]; siv[tix] = inv2[c]; ssh[tix] = sh2[c];
  }
  __syncthreads();

  float S[4][4] = {}, P[4][4] = {}, Q[4][4] = {};
  const float* xb = x + (size_t)b * C_ * T_;
  const unsigned int* hb = htP + (size_t)b * A_ * TP;

  for (int tt = th * 2; tt < th * 2 + 2; tt++) {
    int tb = tt * 128 + wn * 64;
    f32x4 acc[4][4];
#pragma unroll
    for (int mi = 0; mi < 4; mi++)
#pragma unroll
      for (int ni = 0; ni < 4; ni++) acc[mi][ni] = (f32x4){0.f, 0.f, 0.f, 0.f};

    for (int ks = 0; ks < KS2; ks++) {
      bf16x8 bh[4], bl[4];
      int ag = ks * 32 + lg * 8;
#pragma unroll
      for (int ns = 0; ns < 4; ns++) {
        int t = tb + ns * 16 + ll;
#pragma unroll
        for (int j = 0; j < 8; j++) {
          unsigned int v = hb[(size_t)(ag + j) * TP + t];
          bh[ns][j] = (short)(v >> 16);
          bl[ns][j] = (short)(v & 0xffffu);
        }
      }
#pragma unroll
      for (int mi = 0; mi < 4; mi++) {
        size_t fi = ((size_t)((cb * 8 + wm * 4 + mi) * KS2 + ks) * 64 + l) * 8;
        bf16x8 ah = *(const bf16x8*)(W2H + fi);
        bf16x8 al = *(const bf16x8*)(W2L + fi);
#pragma unroll
        for (int ns = 0; ns < 4; ns++) {
          acc[mi][ns] = MFMA(ah, bh[ns], acc[mi][ns]);
          acc[mi][ns] = MFMA(ah, bl[ns], acc[mi][ns]);
          acc[mi][ns] = MFMA(al, bh[ns], acc[mi][ns]);
        }
      }
    }
    // pooling partials (no max-subtraction: z bounded)
#pragma unroll
    for (int ns = 0; ns < 4; ns++) {
      int t = tb + ns * 16 + ll;
      float em = t < T_ ? 1.f : 0.f;
      int   te = t < T_ ? t : T_ - 1;
#pragma unroll
      for (int mi = 0; mi < 4; mi++) {
#pragma unroll
        for (int r = 0; r < 4; r++) {
          int cl = wm * 64 + mi * 16 + lg * 4 + r;
          float h2 = acc[mi][ns][r] + sb2[cl];
          float z  = fmaxf(h2, 0.f) * siv[cl] + ssh[cl];
          float e  = __expf(z) * em;
          float xv = xb[(size_t)(cb * 128 + cl) * T_ + te];
          S[mi][r] += e; P[mi][r] += e * xv; Q[mi][r] += e * xv * xv;
        }
      }
    }
  }

  // reduce over the 16 lanes holding different t within a group
#pragma unroll
  for (int mi = 0; mi < 4; mi++)
#pragma unroll
    for (int r = 0; r < 4; r++)
      for (int d = 1; d < 16; d <<= 1) {
        S[mi][r] += __shfl_xor(S[mi][r], d);
        P[mi][r] += __shfl_xor(P[mi][r], d);
        Q[mi][r] += __shfl_xor(Q[mi][r], d);
      }
  if (ll == 0) {
#pragma unroll
    for (int mi = 0; mi < 4; mi++)
#pragma unroll
      for (int r = 0; r < 4; r++) {
        int cl = wm * 64 + mi * 16 + lg * 4 + r;
        rS[wn][cl] = S[mi][r]; rP[wn][cl] = P[mi][r]; rQ[wn][cl] = Q[mi][r];
      }
  }
  __syncthreads();
  if (tix < 128) {
    int i = b * C_ + cb * 128 + tix;
    atomicAdd(&SS[i], rS[0][tix] + rS[1][tix]);
    atomicAdd(&PP[i], rP[0][tix] + rP[1][tix]);
    atomicAdd(&QQ[i], rQ[0][tix] + rQ[1][tix]);
  }
}

// ---------------- zero partials ----------------
__global__ void k_zero(float* p, int n) {
  int i = blockIdx.x * 256 + threadIdx.x;
  if (i < n) p[i] = 0.f;
}

// ---------------- finish: mu / sg ----------------
__global__ void k_finish(const float* __restrict__ SS, const float* __restrict__ PP,
                         const float* __restrict__ QQ, float* __restrict__ out) {
  int i = blockIdx.x * 256 + threadIdx.x;
  if (i >= B_ * C_) return;
  int b = i / C_, c = i % C_;
  float S = SS[i];
  float mu = PP[i] / S;
  float var = QQ[i] / S - mu * mu;
  out[(size_t)b * 2 * C_ + c]      = mu;
  out[(size_t)b * 2 * C_ + C_ + c] = sqrtf(fmaxf(var, CLAMPV));
}

extern "C" void kernel_launch(void* const* d_in, const int* in_sizes, int n_in,
                              void* d_out, int out_size, void* d_ws, size_t ws_size,
                              hipStream_t stream) {
  const float* x     = (const float*)d_in[0];
  const float* W1    = (const float*)d_in[1];
  const float* b1    = (const float*)d_in[2];
  const float* g1    = (const float*)d_in[3];
  const float* beta1 = (const float*)d_in[4];
  const float* rm1   = (const float*)d_in[5];
  const float* rv1   = (const float*)d_in[6];
  const float* W2    = (const float*)d_in[7];
  const float* b2    = (const float*)d_in[8];
  const float* g2    = (const float*)d_in[9];
  const float* beta2 = (const float*)d_in[10];
  const float* rm2   = (const float*)d_in[11];
  const float* rv2   = (const float*)d_in[12];

  float* ws    = (float*)d_ws;
  float* WT    = ws + WT_OFF;
  float* mean  = ws + MEAN_OFF;
  float* stdv  = ws + STD_OFF;
  float* bias1 = ws + BIAS_OFF;
  float* inv1  = ws + INV1_OFF;
  float* sh1   = ws + SH1_OFF;
  float* inv2  = ws + INV2_OFF;
  float* sh2   = ws + SH2_OFF;
  unsigned short* WxH = (unsigned short*)(ws + WXH_OFF);
  unsigned short* WxL = (unsigned short*)(ws + WXL_OFF);
  unsigned short* W2H = (unsigned short*)(ws + W2H_OFF);
  unsigned short* W2L = (unsigned short*)(ws + W2L_OFF);
  unsigned int*   htP = (unsigned int*)(ws + HTP_OFF);
  float* SS = ws + SS_OFF;
  float* PP = ws + PP_OFF;
  float* QQ = ws + QQ_OFF;
  float* out = (float*)d_out;

  k_bn<<<dim3(6), 256, 0, stream>>>(g1, beta1, rm1, rv1, g2, beta2, rm2, rv2,
                                    inv1, sh1, inv2, sh2);
  k_transpose<<<dim3(96, 4), dim3(32, 8), 0, stream>>>(W1, WT);
  k_pack_w<<<dim3(192), 256, 0, stream>>>(W1, W2, WxH, WxL, W2H, W2L);
  k_zero<<<dim3((3 * B_ * C_ + 255) / 256), 256, 0, stream>>>(SS, 3 * B_ * C_);
  k_stats<<<dim3(B_ * C_ / 4), 256, 0, stream>>>(x, mean, stdv);
  k_bias<<<dim3(B_), 128, 0, stream>>>(WT, b1, mean, stdv, bias1);
  k_gemm1<<<dim3(B_, 8), 256, 0, stream>>>(x, WxH, WxL, bias1, inv1, sh1, htP);
  k_pool<<<dim3(B_, 12, 4), 256, 0, stream>>>(x, htP, W2H, W2L, b2, inv2, sh2, SS, PP, QQ);
  k_finish<<<dim3((B_ * C_ + 255) / 256), 256, 0, stream>>>(SS, PP, QQ, out);
}

// Round 6
// 494.367 us; speedup vs baseline: 4.4563x; 1.1299x over previous
//
#include <hip/hip_runtime.h>
#include <cmath>

#define BN_EPS 1e-5f
#define CLAMPV 1e-4f

static constexpr int B_ = 32, C_ = 1536, T_ = 1000, A_ = 128;
static constexpr int C3 = 3 * C_;
static constexpr int TP = 1024;        // padded T
static constexpr int KS1 = C_ / 32;    // 48
static constexpr int KS2 = A_ / 32;    // 4
static constexpr int OM1 = A_ / 16;    // 8
static constexpr int OM2 = C_ / 16;    // 96

using bf16x8 = __attribute__((ext_vector_type(8))) short;
using f32x4  = __attribute__((ext_vector_type(4))) float;

#define MFMA(a, b, c) __builtin_amdgcn_mfma_f32_16x16x32_bf16(a, b, c, 0, 0, 0)

// ---- ws layout (float-unit offsets) ----
static constexpr size_t WT_OFF    = 0;                      // 2C*A = 393216
static constexpr size_t MEAN_OFF  = 393216;                 // B*C
static constexpr size_t STD_OFF   = MEAN_OFF + 49152;
static constexpr size_t BIASP_OFF = STD_OFF + 49152;        // 8*B*A = 32768
static constexpr size_t BIAS_OFF  = BIASP_OFF + 32768;      // B*A
static constexpr size_t INV1_OFF  = BIAS_OFF + 4096;
static constexpr size_t SH1_OFF   = INV1_OFF + 128;
static constexpr size_t INV2_OFF  = SH1_OFF + 128;
static constexpr size_t SH2_OFF   = INV2_OFF + 1536;
static constexpr size_t WXH_OFF   = SH2_OFF + 1536;         // 98304 each
static constexpr size_t WXL_OFF   = WXH_OFF + 98304;
static constexpr size_t W2H_OFF   = WXL_OFF + 98304;
static constexpr size_t W2L_OFF   = W2H_OFF + 98304;
static constexpr size_t HTP_OFF   = W2L_OFF + 98304;        // B*A*TP = 4194304
static constexpr size_t HPART_OFF = HTP_OFF + 4194304;      // 2*B*A*TP = 8388608
static constexpr size_t SP_OFF    = HPART_OFF + 8388608;    // 8*B*C = 393216
static constexpr size_t PP_OFF    = SP_OFF + 393216;
static constexpr size_t QP_OFF    = PP_OFF + 393216;        // end ~58.8 MB

__device__ __forceinline__ short f2bf(float v) {
  __bf16 b = (__bf16)v;                     // RNE
  return __builtin_bit_cast(short, b);
}
__device__ __forceinline__ float bf2f(short s) {
  unsigned int u = ((unsigned int)(unsigned short)s) << 16;
  return __builtin_bit_cast(float, u);
}

// ---------------- transpose W1 cols [C,3C) -> WT[c'][o] ----------------
__global__ __launch_bounds__(256) void k_transpose(const float* __restrict__ W1,
                                                   float* __restrict__ WT) {
  __shared__ float tile[32][33];
  int c0 = blockIdx.x * 32;   // 96 blocks -> c' in [0,3072)
  int o0 = blockIdx.y * 32;
  int tx = threadIdx.x, ty = threadIdx.y;
#pragma unroll
  for (int k = 0; k < 32; k += 8)
    tile[ty + k][tx] = W1[(size_t)(o0 + ty + k) * C3 + C_ + c0 + tx];
  __syncthreads();
#pragma unroll
  for (int k = 0; k < 32; k += 8)
    WT[(size_t)(c0 + ty + k) * A_ + o0 + tx] = tile[tx][ty + k];
}

// ---------------- per-(b,c) mean / std ----------------
__global__ __launch_bounds__(256) void k_stats(const float* __restrict__ x,
                                               float* __restrict__ mean,
                                               float* __restrict__ stdv) {
  int row  = blockIdx.x * 4 + (threadIdx.x >> 6);
  int lane = threadIdx.x & 63;
  const float2* xr2 = (const float2*)(x + (size_t)row * T_);
  float s1 = 0.f, s2 = 0.f;
#pragma unroll 4
  for (int j = lane; j < T_ / 2; j += 64) {
    float2 v = xr2[j];
    s1 += v.x + v.y;
    s2 += v.x * v.x + v.y * v.y;
  }
#pragma unroll
  for (int off = 32; off; off >>= 1) {
    s1 += __shfl_xor(s1, off);
    s2 += __shfl_xor(s2, off);
  }
  if (lane == 0) {
    float m   = s1 / T_;
    float var = (s2 - s1 * m) / (T_ - 1);
    mean[row] = m;
    stdv[row] = sqrtf(fmaxf(var, CLAMPV));
  }
}

// ---------------- bn scale/shift ----------------
__global__ void k_bn(const float* __restrict__ g1, const float* __restrict__ beta1,
                     const float* __restrict__ rm1, const float* __restrict__ rv1,
                     const float* __restrict__ g2, const float* __restrict__ beta2,
                     const float* __restrict__ rm2, const float* __restrict__ rv2,
                     float* inv1, float* sh1, float* inv2, float* sh2) {
  int i = blockIdx.x * 256 + threadIdx.x;
  if (i < A_) { float iv = g1[i] * rsqrtf(rv1[i] + BN_EPS); inv1[i] = iv; sh1[i] = beta1[i] - rm1[i] * iv; }
  if (i < C_) { float iv = g2[i] * rsqrtf(rv2[i] + BN_EPS); inv2[i] = iv; sh2[i] = beta2[i] - rm2[i] * iv; }
}

// ---------------- pack Wx / W2 hi+lo into MFMA A-frag order ----------------
__global__ __launch_bounds__(256) void k_pack_w(const float* __restrict__ W1,
                                                const float* __restrict__ W2,
                                                unsigned short* __restrict__ WxH,
                                                unsigned short* __restrict__ WxL,
                                                unsigned short* __restrict__ W2H,
                                                unsigned short* __restrict__ W2L) {
  int id = blockIdx.x * 256 + threadIdx.x;
  if (id < OM1 * KS1 * 64) {
    int l = id & 63; int ks = (id >> 6) % KS1; int om = id / (64 * KS1);
    int o  = om * 16 + (l & 15);
    int c0 = ks * 32 + (l >> 4) * 8;
#pragma unroll
    for (int j = 0; j < 8; j++) {
      float v = W1[(size_t)o * C3 + c0 + j];
      short h = f2bf(v); float fh = bf2f(h); short lo = f2bf(v - fh);
      WxH[(size_t)id * 8 + j] = (unsigned short)h;
      WxL[(size_t)id * 8 + j] = (unsigned short)lo;
    }
  } else {
    int id2 = id - OM1 * KS1 * 64;
    int l = id2 & 63; int ks = (id2 >> 6) & 3; int om = id2 / (64 * KS2);
    int cr = om * 16 + (l & 15);
    int a0 = ks * 32 + (l >> 4) * 8;
#pragma unroll
    for (int j = 0; j < 8; j++) {
      float v = W2[(size_t)cr * A_ + a0 + j];
      short h = f2bf(v); float fh = bf2f(h); short lo = f2bf(v - fh);
      W2H[(size_t)id2 * 8 + j] = (unsigned short)h;
      W2L[(size_t)id2 * 8 + j] = (unsigned short)lo;
    }
  }
}

// ---------------- bias partials: grid (B, 8 c-chunks of 192) ----------------
__global__ __launch_bounds__(256) void k_biasPart(const float* __restrict__ WT,
                                                  const float* __restrict__ mean,
                                                  const float* __restrict__ stdv,
                                                  float* __restrict__ biasPart) {
  __shared__ float sm[192], ss[192];
  __shared__ float red[2][128];
  int b = blockIdx.x, cg = blockIdx.y;
  int tix = threadIdx.x;
  if (tix < 192) {
    sm[tix] = mean[b * C_ + cg * 192 + tix];
    ss[tix] = stdv[b * C_ + cg * 192 + tix];
  }
  __syncthreads();
  int o = tix & 127, cs = tix >> 7;
  float acc = 0.f;
#pragma unroll 4
  for (int i = 0; i < 96; i++) {
    int c = cs * 96 + i;
    int cgl = cg * 192 + c;
    acc += sm[c] * WT[(size_t)cgl * A_ + o] + ss[c] * WT[(size_t)(C_ + cgl) * A_ + o];
  }
  red[cs][o] = acc;
  __syncthreads();
  if (tix < 128)
    biasPart[((size_t)cg * B_ + b) * A_ + tix] = red[0][tix] + red[1][tix];
}

__global__ void k_bias2(const float* __restrict__ b1, const float* __restrict__ biasPart,
                        float* __restrict__ bias1) {
  int b = blockIdx.x, o = threadIdx.x;
  float a = b1[o];
#pragma unroll
  for (int g = 0; g < 8; g++) a += biasPart[((size_t)g * B_ + b) * A_ + o];
  bias1[b * A_ + o] = a;
}

// ---------------- GEMM1: split-K raw partials. grid (B, 16 t-tiles, 2 kc) ----------------
// block tile 128o x 64t, 4 waves: wm = o-half, wn = t-half; wave = 64o x 32t
__global__ __launch_bounds__(256, 4) void k_gemm1(const float* __restrict__ x,
    const unsigned short* __restrict__ WxH, const unsigned short* __restrict__ WxL,
    float* __restrict__ hPart) {
  int b = blockIdx.x, tt = blockIdx.y, kc = blockIdx.z;
  int wid = threadIdx.x >> 6, l = threadIdx.x & 63;
  int wm = wid & 1, wn = wid >> 1;
  int lg = l >> 4, ll = l & 15;

  f32x4 acc[4][2];
#pragma unroll
  for (int mi = 0; mi < 4; mi++)
#pragma unroll
    for (int ns = 0; ns < 2; ns++) acc[mi][ns] = (f32x4){0.f, 0.f, 0.f, 0.f};

  const float* xb = x + (size_t)b * C_ * T_;
  int tbase = tt * 64 + wn * 32;
  int   tloc[2];
  float tmask[2];
#pragma unroll
  for (int ns = 0; ns < 2; ns++) {
    int t = tbase + ns * 16 + ll;
    tloc[ns]  = t < T_ ? t : T_ - 1;
    tmask[ns] = t < T_ ? 1.f : 0.f;
  }

  for (int ksl = 0; ksl < KS1 / 2; ksl++) {
    int ks = kc * (KS1 / 2) + ksl;
    bf16x8 ah[4], al[4];
#pragma unroll
    for (int mi = 0; mi < 4; mi++) {
      size_t fi = ((size_t)((wm * 4 + mi) * KS1 + ks) * 64 + l) * 8;
      ah[mi] = *(const bf16x8*)(WxH + fi);
      al[mi] = *(const bf16x8*)(WxL + fi);
    }
    int cg = ks * 32 + lg * 8;
    bf16x8 bh[2], bl[2];
#pragma unroll
    for (int ns = 0; ns < 2; ns++) {
      const float* xp = xb + tloc[ns];
      float m = tmask[ns];
#pragma unroll
      for (int j = 0; j < 8; j++) {
        float v = xp[(size_t)(cg + j) * T_] * m;
        short h = f2bf(v); float fh = bf2f(h); short lo = f2bf(v - fh);
        bh[ns][j] = h; bl[ns][j] = lo;
      }
    }
#pragma unroll
    for (int mi = 0; mi < 4; mi++)
#pragma unroll
      for (int ns = 0; ns < 2; ns++) {
        acc[mi][ns] = MFMA(ah[mi], bh[ns], acc[mi][ns]);
        acc[mi][ns] = MFMA(ah[mi], bl[ns], acc[mi][ns]);
        acc[mi][ns] = MFMA(al[mi], bh[ns], acc[mi][ns]);
      }
  }

#pragma unroll
  for (int mi = 0; mi < 4; mi++)
#pragma unroll
    for (int r = 0; r < 4; r++) {
      int o = wm * 64 + mi * 16 + lg * 4 + r;
#pragma unroll
      for (int ns = 0; ns < 2; ns++) {
        int t = tbase + ns * 16 + ll;
        hPart[(((size_t)kc * B_ + b) * A_ + o) * TP + t] = acc[mi][ns][r];
      }
    }
}

// ---------------- activation: combine kc halves + bias + relu + bn + tanh -> htP ----------------
__global__ __launch_bounds__(256) void k_act(const float* __restrict__ hPart,
                                             const float* __restrict__ bias1,
                                             const float* __restrict__ inv1,
                                             const float* __restrict__ sh1,
                                             unsigned int* __restrict__ htP) {
  int bo = blockIdx.x;                       // b*A + o
  int t  = blockIdx.y * 256 + threadIdx.x;
  int b = bo >> 7, o = bo & 127;
  float v = hPart[(size_t)bo * TP + t] + hPart[((size_t)B_ * A_ + bo) * TP + t]
          + bias1[b * A_ + o];
  v = fmaxf(v, 0.f) * inv1[o] + sh1[o];
  float e  = __expf(2.f * v);
  float th = 1.f - 2.f / (e + 1.f);
  short h = f2bf(th); float fh = bf2f(h); short lo = f2bf(th - fh);
  htP[(size_t)bo * TP + t] = ((unsigned int)(unsigned short)h << 16) | (unsigned short)lo;
}

// ---------------- GEMM2 + relu + bn + exp pooling partial slices ----------------
// grid (B, 12 c-tiles, 8 t-tiles of 128); 8 waves: wm = c-half, wt = t-quarter (32 t)
__global__ __launch_bounds__(512, 4) void k_pool(const float* __restrict__ x,
    const unsigned int* __restrict__ htP,
    const unsigned short* __restrict__ W2H, const unsigned short* __restrict__ W2L,
    const float* __restrict__ b2, const float* __restrict__ inv2, const float* __restrict__ sh2,
    float* __restrict__ SP, float* __restrict__ PP, float* __restrict__ QP) {
  int b = blockIdx.x, cb = blockIdx.y, th = blockIdx.z;
  int tix = threadIdx.x;
  int wid = tix >> 6, l = tix & 63;
  int wm = wid & 1, wt = wid >> 1;
  int lg = l >> 4, ll = l & 15;

  __shared__ float sb2[128], siv[128], ssh[128];
  __shared__ float rS[4][128], rP[4][128], rQ[4][128];
  if (tix < 128) {
    int c = cb * 128 + tix;
    sb2[tix] = b2[c]; siv[tix] = inv2[c]; ssh[tix] = sh2[c];
  }
  __syncthreads();

  f32x4 acc[4][2];
#pragma unroll
  for (int mi = 0; mi < 4; mi++)
#pragma unroll
    for (int ns = 0; ns < 2; ns++) acc[mi][ns] = (f32x4){0.f, 0.f, 0.f, 0.f};

  const unsigned int* hb = htP + (size_t)b * A_ * TP;
  int tb = th * 128 + wt * 32;

  for (int ks = 0; ks < KS2; ks++) {
    bf16x8 bh[2], bl[2];
    int ag = ks * 32 + lg * 8;
#pragma unroll
    for (int ns = 0; ns < 2; ns++) {
      int t = tb + ns * 16 + ll;
#pragma unroll
      for (int j = 0; j < 8; j++) {
        unsigned int v = hb[(size_t)(ag + j) * TP + t];
        bh[ns][j] = (short)(v >> 16);
        bl[ns][j] = (short)(v & 0xffffu);
      }
    }
#pragma unroll
    for (int mi = 0; mi < 4; mi++) {
      size_t fi = ((size_t)((cb * 8 + wm * 4 + mi) * KS2 + ks) * 64 + l) * 8;
      bf16x8 ah = *(const bf16x8*)(W2H + fi);
      bf16x8 al = *(const bf16x8*)(W2L + fi);
#pragma unroll
      for (int ns = 0; ns < 2; ns++) {
        acc[mi][ns] = MFMA(ah, bh[ns], acc[mi][ns]);
        acc[mi][ns] = MFMA(ah, bl[ns], acc[mi][ns]);
        acc[mi][ns] = MFMA(al, bh[ns], acc[mi][ns]);
      }
    }
  }

  const float* xb = x + (size_t)b * C_ * T_;
#pragma unroll
  for (int mi = 0; mi < 4; mi++) {
#pragma unroll
    for (int r = 0; r < 4; r++) {
      int cl = wm * 64 + mi * 16 + lg * 4 + r;
      float s = 0.f, p = 0.f, q = 0.f;
#pragma unroll
      for (int ns = 0; ns < 2; ns++) {
        int t = tb + ns * 16 + ll;
        float em = t < T_ ? 1.f : 0.f;
        int   te = t < T_ ? t : T_ - 1;
        float h2 = acc[mi][ns][r] + sb2[cl];
        float z  = fmaxf(h2, 0.f) * siv[cl] + ssh[cl];
        float e  = __expf(z) * em;
        float xv = xb[(size_t)(cb * 128 + cl) * T_ + te];
        s += e; p += e * xv; q += e * xv * xv;
      }
#pragma unroll
      for (int d = 1; d < 16; d <<= 1) {
        s += __shfl_xor(s, d);
        p += __shfl_xor(p, d);
        q += __shfl_xor(q, d);
      }
      if (ll == 0) { rS[wt][cl] = s; rP[wt][cl] = p; rQ[wt][cl] = q; }
    }
  }
  __syncthreads();
  if (tix < 128) {
    float S = rS[0][tix] + rS[1][tix] + rS[2][tix] + rS[3][tix];
    float P = rP[0][tix] + rP[1][tix] + rP[2][tix] + rP[3][tix];
    float Q = rQ[0][tix] + rQ[1][tix] + rQ[2][tix] + rQ[3][tix];
    size_t o = ((size_t)th * B_ + b) * C_ + cb * 128 + tix;
    SP[o] = S; PP[o] = P; QP[o] = Q;
  }
}

// ---------------- finish: sum 8 t-slices, mu/sg ----------------
__global__ void k_finish(const float* __restrict__ SP, const float* __restrict__ PP,
                         const float* __restrict__ QP, float* __restrict__ out) {
  int i = blockIdx.x * 256 + threadIdx.x;
  if (i >= B_ * C_) return;
  int b = i / C_, c = i % C_;
  float S = 0.f, P = 0.f, Q = 0.f;
#pragma unroll
  for (int t8 = 0; t8 < 8; t8++) {
    size_t o = ((size_t)t8 * B_ + b) * C_ + c;
    S += SP[o]; P += PP[o]; Q += QP[o];
  }
  float mu  = P / S;
  float var = Q / S - mu * mu;
  out[(size_t)b * 2 * C_ + c]      = mu;
  out[(size_t)b * 2 * C_ + C_ + c] = sqrtf(fmaxf(var, CLAMPV));
}

extern "C" void kernel_launch(void* const* d_in, const int* in_sizes, int n_in,
                              void* d_out, int out_size, void* d_ws, size_t ws_size,
                              hipStream_t stream) {
  const float* x     = (const float*)d_in[0];
  const float* W1    = (const float*)d_in[1];
  const float* b1    = (const float*)d_in[2];
  const float* g1    = (const float*)d_in[3];
  const float* beta1 = (const float*)d_in[4];
  const float* rm1   = (const float*)d_in[5];
  const float* rv1   = (const float*)d_in[6];
  const float* W2    = (const float*)d_in[7];
  const float* b2    = (const float*)d_in[8];
  const float* g2    = (const float*)d_in[9];
  const float* beta2 = (const float*)d_in[10];
  const float* rm2   = (const float*)d_in[11];
  const float* rv2   = (const float*)d_in[12];

  float* ws     = (float*)d_ws;
  float* WT     = ws + WT_OFF;
  float* mean   = ws + MEAN_OFF;
  float* stdv   = ws + STD_OFF;
  float* biasP  = ws + BIASP_OFF;
  float* bias1  = ws + BIAS_OFF;
  float* inv1   = ws + INV1_OFF;
  float* sh1    = ws + SH1_OFF;
  float* inv2   = ws + INV2_OFF;
  float* sh2    = ws + SH2_OFF;
  unsigned short* WxH = (unsigned short*)(ws + WXH_OFF);
  unsigned short* WxL = (unsigned short*)(ws + WXL_OFF);
  unsigned short* W2H = (unsigned short*)(ws + W2H_OFF);
  unsigned short* W2L = (unsigned short*)(ws + W2L_OFF);
  unsigned int*   htP = (unsigned int*)(ws + HTP_OFF);
  float* hPart  = ws + HPART_OFF;
  float* SP = ws + SP_OFF;
  float* PP = ws + PP_OFF;
  float* QP = ws + QP_OFF;
  float* out = (float*)d_out;

  k_bn<<<dim3(6), 256, 0, stream>>>(g1, beta1, rm1, rv1, g2, beta2, rm2, rv2,
                                    inv1, sh1, inv2, sh2);
  k_transpose<<<dim3(96, 4), dim3(32, 8), 0, stream>>>(W1, WT);
  k_pack_w<<<dim3(192), 256, 0, stream>>>(W1, W2, WxH, WxL, W2H, W2L);
  k_stats<<<dim3(B_ * C_ / 4), 256, 0, stream>>>(x, mean, stdv);
  k_biasPart<<<dim3(B_, 8), 256, 0, stream>>>(WT, mean, stdv, biasP);
  k_bias2<<<dim3(B_), 128, 0, stream>>>(b1, biasP, bias1);
  k_gemm1<<<dim3(B_, 16, 2), 256, 0, stream>>>(x, WxH, WxL, hPart);
  k_act<<<dim3(B_ * A_, TP / 256), 256, 0, stream>>>(hPart, bias1, inv1, sh1, htP);
  k_pool<<<dim3(B_, 12, 8), 512, 0, stream>>>(x, htP, W2H, W2L, b2, inv2, sh2, SP, PP, QP);
  k_finish<<<dim3((B_ * C_ + 255) / 256), 256, 0, stream>>>(SP, PP, QP, out);
}

// Round 12
// 491.144 us; speedup vs baseline: 4.4856x; 1.0066x over previous
//
#include <hip/hip_runtime.h>
#include <cmath>

#define BN_EPS 1e-5f
#define CLAMPV 1e-4f

static constexpr int B_ = 32, C_ = 1536, T_ = 1000, A_ = 128;
static constexpr int C3 = 3 * C_;
static constexpr int TP = 1024;        // padded T
static constexpr int KS1 = C_ / 32;    // 48
static constexpr int KS2 = A_ / 32;    // 4
static constexpr int OM1 = A_ / 16;    // 8

using bf16x8 = __attribute__((ext_vector_type(8))) short;
using f32x4  = __attribute__((ext_vector_type(4))) float;

#define MFMA(a, b, c) __builtin_amdgcn_mfma_f32_16x16x32_bf16(a, b, c, 0, 0, 0)

// ---- ws layout (float-unit offsets) ----
static constexpr size_t WT_OFF    = 0;                      // 2C*A = 393216
static constexpr size_t MEAN_OFF  = 393216;                 // B*C
static constexpr size_t STD_OFF   = MEAN_OFF + 49152;
static constexpr size_t BIASP_OFF = STD_OFF + 49152;        // 8*B*A
static constexpr size_t BIAS_OFF  = BIASP_OFF + 32768;      // B*A
static constexpr size_t INV1_OFF  = BIAS_OFF + 4096;
static constexpr size_t SH1_OFF   = INV1_OFF + 128;
static constexpr size_t INV2_OFF  = SH1_OFF + 128;
static constexpr size_t SH2_OFF   = INV2_OFF + 1536;
static constexpr size_t WXH_OFF   = SH2_OFF + 1536;         // 98304 each
static constexpr size_t WXL_OFF   = WXH_OFF + 98304;
static constexpr size_t W2H_OFF   = WXL_OFF + 98304;
static constexpr size_t W2L_OFF   = W2H_OFF + 98304;
static constexpr size_t HTT_OFF   = W2L_OFF + 98304;        // B*TP*A ushort = 2097152 f
static constexpr size_t HPART_OFF = HTT_OFF + 2097152;      // 2*B*TP*A = 8388608
static constexpr size_t SP_OFF    = HPART_OFF + 8388608;    // 8*B*C
static constexpr size_t PP_OFF    = SP_OFF + 393216;
static constexpr size_t QP_OFF    = PP_OFF + 393216;        // end ~50.4 MB (floats)

__device__ __forceinline__ short f2bf(float v) {
  __bf16 b = (__bf16)v;                     // RNE
  return __builtin_bit_cast(short, b);
}
__device__ __forceinline__ float bf2f(short s) {
  unsigned int u = ((unsigned int)(unsigned short)s) << 16;
  return __builtin_bit_cast(float, u);
}

// ---------------- transpose W1 cols [C,3C) -> WT[c'][o] ----------------
__global__ __launch_bounds__(256) void k_transpose(const float* __restrict__ W1,
                                                   float* __restrict__ WT) {
  __shared__ float tile[32][33];
  int c0 = blockIdx.x * 32;
  int o0 = blockIdx.y * 32;
  int tx = threadIdx.x, ty = threadIdx.y;
#pragma unroll
  for (int k = 0; k < 32; k += 8)
    tile[ty + k][tx] = W1[(size_t)(o0 + ty + k) * C3 + C_ + c0 + tx];
  __syncthreads();
#pragma unroll
  for (int k = 0; k < 32; k += 8)
    WT[(size_t)(c0 + ty + k) * A_ + o0 + tx] = tile[tx][ty + k];
}

// ---------------- per-(b,c) mean / std ----------------
__global__ __launch_bounds__(256) void k_stats(const float* __restrict__ x,
                                               float* __restrict__ mean,
                                               float* __restrict__ stdv) {
  int row  = blockIdx.x * 4 + (threadIdx.x >> 6);
  int lane = threadIdx.x & 63;
  const float2* xr2 = (const float2*)(x + (size_t)row * T_);
  float s1 = 0.f, s2 = 0.f;
#pragma unroll 4
  for (int j = lane; j < T_ / 2; j += 64) {
    float2 v = xr2[j];
    s1 += v.x + v.y;
    s2 += v.x * v.x + v.y * v.y;
  }
#pragma unroll
  for (int off = 32; off; off >>= 1) {
    s1 += __shfl_xor(s1, off);
    s2 += __shfl_xor(s2, off);
  }
  if (lane == 0) {
    float m   = s1 / T_;
    float var = (s2 - s1 * m) / (T_ - 1);
    mean[row] = m;
    stdv[row] = sqrtf(fmaxf(var, CLAMPV));
  }
}

// ---------------- bn scale/shift ----------------
__global__ void k_bn(const float* __restrict__ g1, const float* __restrict__ beta1,
                     const float* __restrict__ rm1, const float* __restrict__ rv1,
                     const float* __restrict__ g2, const float* __restrict__ beta2,
                     const float* __restrict__ rm2, const float* __restrict__ rv2,
                     float* inv1, float* sh1, float* inv2, float* sh2) {
  int i = blockIdx.x * 256 + threadIdx.x;
  if (i < A_) { float iv = g1[i] * rsqrtf(rv1[i] + BN_EPS); inv1[i] = iv; sh1[i] = beta1[i] - rm1[i] * iv; }
  if (i < C_) { float iv = g2[i] * rsqrtf(rv2[i] + BN_EPS); inv2[i] = iv; sh2[i] = beta2[i] - rm2[i] * iv; }
}

// ---------------- pack Wx / W2 hi+lo into MFMA A-frag order ----------------
__global__ __launch_bounds__(256) void k_pack_w(const float* __restrict__ W1,
                                                const float* __restrict__ W2,
                                                unsigned short* __restrict__ WxH,
                                                unsigned short* __restrict__ WxL,
                                                unsigned short* __restrict__ W2H,
                                                unsigned short* __restrict__ W2L) {
  int id = blockIdx.x * 256 + threadIdx.x;
  if (id < OM1 * KS1 * 64) {
    int l = id & 63; int ks = (id >> 6) % KS1; int om = id / (64 * KS1);
    int o  = om * 16 + (l & 15);
    int c0 = ks * 32 + (l >> 4) * 8;
#pragma unroll
    for (int j = 0; j < 8; j++) {
      float v = W1[(size_t)o * C3 + c0 + j];
      short h = f2bf(v); float fh = bf2f(h); short lo = f2bf(v - fh);
      WxH[(size_t)id * 8 + j] = (unsigned short)h;
      WxL[(size_t)id * 8 + j] = (unsigned short)lo;
    }
  } else {
    int id2 = id - OM1 * KS1 * 64;
    int l = id2 & 63; int ks = (id2 >> 6) & 3; int om = id2 / (64 * KS2);
    int cr = om * 16 + (l & 15);
    int a0 = ks * 32 + (l >> 4) * 8;
#pragma unroll
    for (int j = 0; j < 8; j++) {
      float v = W2[(size_t)cr * A_ + a0 + j];
      short h = f2bf(v); float fh = bf2f(h); short lo = f2bf(v - fh);
      W2H[(size_t)id2 * 8 + j] = (unsigned short)h;
      W2L[(size_t)id2 * 8 + j] = (unsigned short)lo;
    }
  }
}

// ---------------- bias partials: grid (B, 8 c-chunks of 192) ----------------
__global__ __launch_bounds__(256) void k_biasPart(const float* __restrict__ WT,
                                                  const float* __restrict__ mean,
                                                  const float* __restrict__ stdv,
                                                  float* __restrict__ biasPart) {
  __shared__ float sm[192], ss[192];
  __shared__ float red[2][128];
  int b = blockIdx.x, cg = blockIdx.y;
  int tix = threadIdx.x;
  if (tix < 192) {
    sm[tix] = mean[b * C_ + cg * 192 + tix];
    ss[tix] = stdv[b * C_ + cg * 192 + tix];
  }
  __syncthreads();
  int o = tix & 127, cs = tix >> 7;
  float acc = 0.f;
#pragma unroll 4
  for (int i = 0; i < 96; i++) {
    int c = cs * 96 + i;
    int cgl = cg * 192 + c;
    acc += sm[c] * WT[(size_t)cgl * A_ + o] + ss[c] * WT[(size_t)(C_ + cgl) * A_ + o];
  }
  red[cs][o] = acc;
  __syncthreads();
  if (tix < 128)
    biasPart[((size_t)cg * B_ + b) * A_ + tix] = red[0][tix] + red[1][tix];
}

__global__ void k_bias2(const float* __restrict__ b1, const float* __restrict__ biasPart,
                        float* __restrict__ bias1) {
  int b = blockIdx.x, o = threadIdx.x;
  float a = b1[o];
#pragma unroll
  for (int g = 0; g < 8; g++) a += biasPart[((size_t)g * B_ + b) * A_ + o];
  bias1[b * A_ + o] = a;
}

// ---------------- GEMM1: split-K, A=hi+lo, B=hi only. grid (B, 16, 2) ----------------
// out layout hPart[kc][b][t][a], dwordx4 stores
__global__ __launch_bounds__(256, 4) void k_gemm1(const float* __restrict__ x,
    const unsigned short* __restrict__ WxH, const unsigned short* __restrict__ WxL,
    float* __restrict__ hPart) {
  int b = blockIdx.x, tt = blockIdx.y, kc = blockIdx.z;
  int wid = threadIdx.x >> 6, l = threadIdx.x & 63;
  int wm = wid & 1, wn = wid >> 1;
  int lg = l >> 4, ll = l & 15;

  f32x4 acc[4][2];
#pragma unroll
  for (int mi = 0; mi < 4; mi++)
#pragma unroll
    for (int ns = 0; ns < 2; ns++) acc[mi][ns] = (f32x4){0.f, 0.f, 0.f, 0.f};

  const float* xb = x + (size_t)b * C_ * T_;
  int tbase = tt * 64 + wn * 32;
  int   tloc[2];
  float tmask[2];
#pragma unroll
  for (int ns = 0; ns < 2; ns++) {
    int t = tbase + ns * 16 + ll;
    tloc[ns]  = t < T_ ? t : T_ - 1;
    tmask[ns] = t < T_ ? 1.f : 0.f;
  }

  for (int ksl = 0; ksl < KS1 / 2; ksl++) {
    int ks = kc * (KS1 / 2) + ksl;
    bf16x8 ah[4], al[4];
#pragma unroll
    for (int mi = 0; mi < 4; mi++) {
      size_t fi = ((size_t)((wm * 4 + mi) * KS1 + ks) * 64 + l) * 8;
      ah[mi] = *(const bf16x8*)(WxH + fi);
      al[mi] = *(const bf16x8*)(WxL + fi);
    }
    int cg = ks * 32 + lg * 8;
    bf16x8 bh[2];
#pragma unroll
    for (int ns = 0; ns < 2; ns++) {
      const float* xp = xb + tloc[ns];
      float m = tmask[ns];
#pragma unroll
      for (int j = 0; j < 8; j++) {
        float v = xp[(size_t)(cg + j) * T_] * m;
        bh[ns][j] = f2bf(v);
      }
    }
#pragma unroll
    for (int mi = 0; mi < 4; mi++)
#pragma unroll
      for (int ns = 0; ns < 2; ns++) {
        acc[mi][ns] = MFMA(ah[mi], bh[ns], acc[mi][ns]);
        acc[mi][ns] = MFMA(al[mi], bh[ns], acc[mi][ns]);
      }
  }

  float* hp = hPart + ((size_t)kc * B_ + b) * TP * A_;
#pragma unroll
  for (int mi = 0; mi < 4; mi++)
#pragma unroll
    for (int ns = 0; ns < 2; ns++) {
      int t = tbase + ns * 16 + ll;
      int o = wm * 64 + mi * 16 + lg * 4;
      *(f32x4*)(hp + (size_t)t * A_ + o) = acc[mi][ns];
    }
}

// ---------------- activation: combine kc halves + bias + relu + bn + tanh -> htT bf16 ----------------
// htT[b][t][a]; grid (B, TP/2), 256 thr = 2t x 128a
__global__ __launch_bounds__(256) void k_act(const float* __restrict__ hPart,
                                             const float* __restrict__ bias1,
                                             const float* __restrict__ inv1,
                                             const float* __restrict__ sh1,
                                             unsigned short* __restrict__ htT) {
  int b = blockIdx.x;
  int t = blockIdx.y * 2 + (threadIdx.x >> 7);
  int a = threadIdx.x & 127;
  size_t i0 = ((size_t)b * TP + t) * A_ + a;
  float v = hPart[i0] + hPart[(size_t)B_ * TP * A_ + i0] + bias1[b * A_ + a];
  v = fmaxf(v, 0.f) * inv1[a] + sh1[a];
  float e  = __expf(2.f * v);
  float th = 1.f - 2.f / (e + 1.f);
  htT[i0] = (unsigned short)f2bf(th);
}

// ---------------- GEMM2 + relu + bn + exp pooling partial slices ----------------
// A = W2 hi+lo, B = htT bf16 (single). grid (B, 12, 8); 8 waves
__global__ __launch_bounds__(512, 4) void k_pool(const float* __restrict__ x,
    const unsigned short* __restrict__ htT,
    const unsigned short* __restrict__ W2H, const unsigned short* __restrict__ W2L,
    const float* __restrict__ b2, const float* __restrict__ inv2, const float* __restrict__ sh2,
    float* __restrict__ SP, float* __restrict__ PP, float* __restrict__ QP) {
  int b = blockIdx.x, cb = blockIdx.y, th = blockIdx.z;
  int tix = threadIdx.x;
  int wid = tix >> 6, l = tix & 63;
  int wm = wid & 1, wt = wid >> 1;
  int lg = l >> 4, ll = l & 15;

  __shared__ float sb2[128], siv[128], ssh[128];
  __shared__ float rS[4][128], rP[4][128], rQ[4][128];
  if (tix < 128) {
    int c = cb * 128 + tix;
    sb2[tix] = b2[c]; siv[tix] = inv2[c]; ssh[tix] = sh2[c];
  }
  __syncthreads();

  f32x4 acc[4][2];
#pragma unroll
  for (int mi = 0; mi < 4; mi++)
#pragma unroll
    for (int ns = 0; ns < 2; ns++) acc[mi][ns] = (f32x4){0.f, 0.f, 0.f, 0.f};

  const unsigned short* hb = htT + (size_t)b * TP * A_;
  int tb = th * 128 + wt * 32;

  for (int ks = 0; ks < KS2; ks++) {
    int ag = ks * 32 + lg * 8;
    bf16x8 bh[2];
#pragma unroll
    for (int ns = 0; ns < 2; ns++) {
      int t = tb + ns * 16 + ll;
      bh[ns] = *(const bf16x8*)(hb + (size_t)t * A_ + ag);
    }
#pragma unroll
    for (int mi = 0; mi < 4; mi++) {
      size_t fi = ((size_t)((cb * 8 + wm * 4 + mi) * KS2 + ks) * 64 + l) * 8;
      bf16x8 ah = *(const bf16x8*)(W2H + fi);
      bf16x8 al = *(const bf16x8*)(W2L + fi);
#pragma unroll
      for (int ns = 0; ns < 2; ns++) {
        acc[mi][ns] = MFMA(ah, bh[ns], acc[mi][ns]);
        acc[mi][ns] = MFMA(al, bh[ns], acc[mi][ns]);
      }
    }
  }

  const float* xb = x + (size_t)b * C_ * T_;
#pragma unroll
  for (int mi = 0; mi < 4; mi++) {
#pragma unroll
    for (int r = 0; r < 4; r++) {
      int cl = wm * 64 + mi * 16 + lg * 4 + r;
      float s = 0.f, p = 0.f, q = 0.f;
#pragma unroll
      for (int ns = 0; ns < 2; ns++) {
        int t = tb + ns * 16 + ll;
        float em = t < T_ ? 1.f : 0.f;
        int   te = t < T_ ? t : T_ - 1;
        float h2 = acc[mi][ns][r] + sb2[cl];
        float z  = fmaxf(h2, 0.f) * siv[cl] + ssh[cl];
        float e  = __expf(z) * em;
        float xv = xb[(size_t)(cb * 128 + cl) * T_ + te];
        s += e; p += e * xv; q += e * xv * xv;
      }
#pragma unroll
      for (int d = 1; d < 16; d <<= 1) {
        s += __shfl_xor(s, d);
        p += __shfl_xor(p, d);
        q += __shfl_xor(q, d);
      }
      if (ll == 0) { rS[wt][cl] = s; rP[wt][cl] = p; rQ[wt][cl] = q; }
    }
  }
  __syncthreads();
  if (tix < 128) {
    float S = rS[0][tix] + rS[1][tix] + rS[2][tix] + rS[3][tix];
    float P = rP[0][tix] + rP[1][tix] + rP[2][tix] + rP[3][tix];
    float Q = rQ[0][tix] + rQ[1][tix] + rQ[2][tix] + rQ[3][tix];
    size_t o = ((size_t)th * B_ + b) * C_ + cb * 128 + tix;
    SP[o] = S; PP[o] = P; QP[o] = Q;
  }
}

// ---------------- finish: sum 8 t-slices, mu/sg ----------------
__global__ void k_finish(const float* __restrict__ SP, const float* __restrict__ PP,
                         const float* __restrict__ QP, float* __restrict__ out) {
  int i = blockIdx.x * 256 + threadIdx.x;
  if (i >= B_ * C_) return;
  int b = i / C_, c = i % C_;
  float S = 0.f, P = 0.f, Q = 0.f;
#pragma unroll
  for (int t8 = 0; t8 < 8; t8++) {
    size_t o = ((size_t)t8 * B_ + b) * C_ + c;
    S += SP[o]; P += PP[o]; Q += QP[o];
  }
  float mu  = P / S;
  float var = Q / S - mu * mu;
  out[(size_t)b * 2 * C_ + c]      = mu;
  out[(size_t)b * 2 * C_ + C_ + c] = sqrtf(fmaxf(var, CLAMPV));
}

extern "C" void kernel_launch(void* const* d_in, const int* in_sizes, int n_in,
                              void* d_out, int out_size, void* d_ws, size_t ws_size,
                              hipStream_t stream) {
  const float* x     = (const float*)d_in[0];
  const float* W1    = (const float*)d_in[1];
  const float* b1    = (const float*)d_in[2];
  const float* g1    = (const float*)d_in[3];
  const float* beta1 = (const float*)d_in[4];
  const float* rm1   = (const float*)d_in[5];
  const float* rv1   = (const float*)d_in[6];
  const float* W2    = (const float*)d_in[7];
  const float* b2    = (const float*)d_in[8];
  const float* g2    = (const float*)d_in[9];
  const float* beta2 = (const float*)d_in[10];
  const float* rm2   = (const float*)d_in[11];
  const float* rv2   = (const float*)d_in[12];

  float* ws     = (float*)d_ws;
  float* WT     = ws + WT_OFF;
  float* mean   = ws + MEAN_OFF;
  float* stdv   = ws + STD_OFF;
  float* biasP  = ws + BIASP_OFF;
  float* bias1  = ws + BIAS_OFF;
  float* inv1   = ws + INV1_OFF;
  float* sh1    = ws + SH1_OFF;
  float* inv2   = ws + INV2_OFF;
  float* sh2    = ws + SH2_OFF;
  unsigned short* WxH = (unsigned short*)(ws + WXH_OFF);
  unsigned short* WxL = (unsigned short*)(ws + WXL_OFF);
  unsigned short* W2H = (unsigned short*)(ws + W2H_OFF);
  unsigned short* W2L = (unsigned short*)(ws + W2L_OFF);
  unsigned short* htT = (unsigned short*)(ws + HTT_OFF);
  float* hPart  = ws + HPART_OFF;
  float* SP = ws + SP_OFF;
  float* PP = ws + PP_OFF;
  float* QP = ws + QP_OFF;
  float* out = (float*)d_out;

  k_bn<<<dim3(6), 256, 0, stream>>>(g1, beta1, rm1, rv1, g2, beta2, rm2, rv2,
                                    inv1, sh1, inv2, sh2);
  k_transpose<<<dim3(96, 4), dim3(32, 8), 0, stream>>>(W1, WT);
  k_pack_w<<<dim3(192), 256, 0, stream>>>(W1, W2, WxH, WxL, W2H, W2L);
  k_stats<<<dim3(B_ * C_ / 4), 256, 0, stream>>>(x, mean, stdv);
  k_biasPart<<<dim3(B_, 8), 256, 0, stream>>>(WT, mean, stdv, biasP);
  k_bias2<<<dim3(B_), 128, 0, stream>>>(b1, biasP, bias1);
  k_gemm1<<<dim3(B_, 16, 2), 256, 0, stream>>>(x, WxH, WxL, hPart);
  k_act<<<dim3(B_, TP / 2), 256, 0, stream>>>(hPart, bias1, inv1, sh1, htT);
  k_pool<<<dim3(B_, 12, 8), 512, 0, stream>>>(x, htT, W2H, W2L, b2, inv2, sh2, SP, PP, QP);
  k_finish<<<dim3((B_ * C_ + 255) / 256), 256, 0, stream>>>(SP, PP, QP, out);
}